// Round 4
// baseline (429.132 us; speedup 1.0000x reference)
//
#include <hip/hip_runtime.h>

#define B_ 32
#define D_ 512
// x: [32,64,512], W1/W2: [64,64,64] (m,n,k), proj_w: [64,128], proj_b: [64]
// ln_gamma/ln_beta: [512]. Output: [32,64,512] f32.
// Needs 8 MB of d_ws for X1, X2 intermediates.

// Xn[b,k,d] = relu( sum_{m,n} Xk[b,m,d] * X0[b,n,d] * W[m,n,k] )
// Block: one (b, 32-column d-tile). 256 threads: kg = tid&15 (k-quad), cq = tid>>4 (col-pair).
__global__ __launch_bounds__(256) void layer_kernel(
    const float* __restrict__ Xk, const float* __restrict__ X0,
    const float* __restrict__ W, float* __restrict__ Xn) {
  __shared__ float u_lds[64 * 32];   // [m][c]
  __shared__ float v_lds[64 * 32];   // [n][c]
  __shared__ float w_lds[64 * 64];   // [n][k] for current m

  const int tid = threadIdx.x;
  const int b = blockIdx.x >> 4;          // 16 d-tiles of 32
  const int d0 = (blockIdx.x & 15) << 5;  // column base

  // stage u = Xk[b,:,d0:d0+32], v = X0[b,:,d0:d0+32]
  for (int i = tid; i < 2048; i += 256) {
    const int m = i >> 5, c = i & 31;
    const int g = ((b << 6) + m) * D_ + d0 + c;
    u_lds[i] = Xk[g];
    v_lds[i] = X0[g];
  }

  const int kg = tid & 15, cq = tid >> 4;
  const int k0 = kg << 2, c0 = cq << 1;

  float acc[4][2] = {{0.f, 0.f}, {0.f, 0.f}, {0.f, 0.f}, {0.f, 0.f}};

  // prefetch W slice m=0 into registers (float4-vectorized)
  float4 wreg[4];
  {
    const float4* Wp4 = (const float4*)W;
    #pragma unroll
    for (int j = 0; j < 4; ++j) wreg[j] = Wp4[tid + (j << 8)];
  }

  for (int m = 0; m < 64; ++m) {
    __syncthreads();  // all waves done reading w_lds from previous m
    #pragma unroll
    for (int j = 0; j < 4; ++j) ((float4*)w_lds)[tid + (j << 8)] = wreg[j];
    if (m < 63) {  // prefetch next slice; latency hides under compute below
      const float4* Wn4 = (const float4*)(W + ((m + 1) << 12));
      #pragma unroll
      for (int j = 0; j < 4; ++j) wreg[j] = Wn4[tid + (j << 8)];
    }
    __syncthreads();  // w_lds[m] visible

    const float2 um = *(const float2*)&u_lds[(m << 5) + c0];
    #pragma unroll 8
    for (int n = 0; n < 64; ++n) {
      const float2 vn = *(const float2*)&v_lds[(n << 5) + c0];
      const float4 wq = *(const float4*)&w_lds[(n << 6) + k0];
      const float t0 = um.x * vn.x;
      const float t1 = um.y * vn.y;
      acc[0][0] += wq.x * t0; acc[0][1] += wq.x * t1;
      acc[1][0] += wq.y * t0; acc[1][1] += wq.y * t1;
      acc[2][0] += wq.z * t0; acc[2][1] += wq.z * t1;
      acc[3][0] += wq.w * t0; acc[3][1] += wq.w * t1;
    }
  }

  // store with relu: Xn[b, k0+kk, d0+c0 + {0,1}]
  float* outp = Xn + (b << 6) * D_ + d0 + c0;
  #pragma unroll
  for (int kk = 0; kk < 4; ++kk) {
    float2 r;
    r.x = fmaxf(acc[kk][0], 0.f);
    r.y = fmaxf(acc[kk][1], 0.f);
    *(float2*)&outp[(k0 + kk) * D_] = r;
  }
}

// out[b,p,d] = x + sum_t cin[b,t,d]*pw[p,t] + pb[p], then LayerNorm over d.
// Block per (b,p) row; 256 threads x 2 columns each.
__global__ __launch_bounds__(256) void proj_ln_kernel(
    const float* __restrict__ x, const float* __restrict__ X1,
    const float* __restrict__ X2, const float* __restrict__ pw,
    const float* __restrict__ pb, const float* __restrict__ gamma,
    const float* __restrict__ beta, float* __restrict__ out) {
  const int b = blockIdx.x >> 6, p = blockIdx.x & 63;
  const int tid = threadIdx.x;
  const float* x1b = X1 + (b << 6) * D_;
  const float* x2b = X2 + (b << 6) * D_;
  const float* pwr = pw + (p << 7);  // block-uniform -> scalar loads

  float s0 = 0.f, s1 = 0.f;
  #pragma unroll 4
  for (int t = 0; t < 64; ++t) {
    const float w = pwr[t];
    s0 += w * x1b[t * D_ + tid];
    s1 += w * x1b[t * D_ + tid + 256];
  }
  #pragma unroll 4
  for (int t = 0; t < 64; ++t) {
    const float w = pwr[64 + t];
    s0 += w * x2b[t * D_ + tid];
    s1 += w * x2b[t * D_ + tid + 256];
  }

  const float bias = pb[p];
  const int row = (b << 6) + p;
  const float y0 = x[row * D_ + tid] + s0 + bias;
  const float y1 = x[row * D_ + tid + 256] + s1 + bias;

  // block reduction for mean / var over 512 values
  float s = y0 + y1;
  float sq = y0 * y0 + y1 * y1;
  #pragma unroll
  for (int off = 32; off > 0; off >>= 1) {
    s += __shfl_down(s, off);
    sq += __shfl_down(sq, off);
  }
  __shared__ float red[8];
  const int wv = tid >> 6;
  if ((tid & 63) == 0) { red[wv] = s; red[4 + wv] = sq; }
  __syncthreads();
  const float sum = red[0] + red[1] + red[2] + red[3];
  const float sumsq = red[4] + red[5] + red[6] + red[7];
  const float mu = sum * (1.f / 512.f);
  const float var = sumsq * (1.f / 512.f) - mu * mu;
  const float rs = rsqrtf(var + 1e-5f);

  out[row * D_ + tid] = gamma[tid] * (y0 - mu) * rs + beta[tid];
  out[row * D_ + tid + 256] = gamma[tid + 256] * (y1 - mu) * rs + beta[tid + 256];
}

extern "C" void kernel_launch(void* const* d_in, const int* in_sizes, int n_in,
                              void* d_out, int out_size, void* d_ws, size_t ws_size,
                              hipStream_t stream) {
  const float* x     = (const float*)d_in[0];
  const float* W1    = (const float*)d_in[1];
  const float* W2    = (const float*)d_in[2];
  const float* pw    = (const float*)d_in[3];
  const float* pb    = (const float*)d_in[4];
  const float* gamma = (const float*)d_in[5];
  const float* beta  = (const float*)d_in[6];
  float* out = (float*)d_out;

  float* X1 = (float*)d_ws;              // [32,64,512] f32 = 4 MB
  float* X2 = X1 + 32 * 64 * 512;        // 4 MB

  layer_kernel<<<dim3(512), dim3(256), 0, stream>>>(x, x, W1, X1);
  layer_kernel<<<dim3(512), dim3(256), 0, stream>>>(X1, x, W2, X2);
  proj_ln_kernel<<<dim3(2048), dim3(256), 0, stream>>>(x, X1, X2, pw, pb, gamma, beta, out);
}

// Round 5
// 191.351 us; speedup vs baseline: 2.2426x; 2.2426x over previous
//
#include <hip/hip_runtime.h>

typedef __attribute__((ext_vector_type(8))) short bf16x8;
typedef __attribute__((ext_vector_type(4))) float f32x4;
typedef __attribute__((ext_vector_type(8))) unsigned short u16x8;

__device__ __forceinline__ unsigned short f2bf(float f) {
  union { float f; unsigned u; } v; v.f = f;
  unsigned r = v.u + 0x7FFF + ((v.u >> 16) & 1);
  return (unsigned short)(r >> 16);
}
__device__ __forceinline__ float bf2f(unsigned short s) {
  union { unsigned u; float f; } v; v.u = ((unsigned)s) << 16;
  return v.f;
}

// x[32][64][512] f32 -> xt[32][512][64] bf16 (transpose m<->d per b)
__global__ __launch_bounds__(256) void transpose_x(const float* __restrict__ x,
                                                   unsigned short* __restrict__ xt) {
  __shared__ float xs[64 * 64];  // [m][d-local]
  const int b = blockIdx.x >> 3, d0 = (blockIdx.x & 7) << 6;
  const int t = threadIdx.x;
  #pragma unroll
  for (int i = 0; i < 4; ++i) {
    const int idx = i * 256 + t;            // m = idx>>4, c = idx&15
    const int m = idx >> 4, c = idx & 15;
    float4 v = *(const float4*)&x[((b << 6) + m) * 512 + d0 + (c << 2)];
    *(float4*)&xs[(m << 6) + (c << 2)] = v;
  }
  __syncthreads();
  #pragma unroll
  for (int j = 0; j < 2; ++j) {
    const int idx = j * 256 + t;            // row dl = idx>>3, m-chunk g = idx&7
    const int dl = idx >> 3, g = idx & 7;
    u16x8 o;
    #pragma unroll
    for (int jj = 0; jj < 8; ++jj) o[jj] = f2bf(xs[(((g << 3) + jj) << 6) + dl]);
    *(u16x8*)&xt[((b * 512) + d0 + dl) * 64 + (g << 3)] = o;
  }
}

// W[m][n][k] f32 -> Wt[m][k][n] bf16, with 16B-chunk XOR swizzle: chunk slot = g ^ (k&7)
__global__ __launch_bounds__(256) void transpose_w(const float* __restrict__ W1,
                                                   const float* __restrict__ W2,
                                                   unsigned short* __restrict__ W1t,
                                                   unsigned short* __restrict__ W2t) {
  __shared__ float ws_[64 * 64];  // [n][k]
  const int m = blockIdx.x & 63, sel = blockIdx.x >> 6;
  const float* src = (sel ? W2 : W1) + m * 4096;
  unsigned short* dst = (sel ? W2t : W1t) + m * 4096;
  const int t = threadIdx.x;
  #pragma unroll
  for (int i = 0; i < 4; ++i) {
    const int idx = i * 256 + t;
    *(float4*)&ws_[idx << 2] = *(const float4*)&src[idx << 2];
  }
  __syncthreads();
  #pragma unroll
  for (int j = 0; j < 2; ++j) {
    const int idx = j * 256 + t;            // row k = idx>>3, content chunk g = idx&7
    const int k = idx >> 3, g = idx & 7;
    u16x8 o;
    #pragma unroll
    for (int jj = 0; jj < 8; ++jj) o[jj] = f2bf(ws_[(((g << 3) + jj) << 6) + k]);
    const int slot = g ^ (k & 7);
    *(u16x8*)&dst[(k << 6) + (slot << 3)] = o;
  }
}

// Xn_t[b][d][k] = relu( sum_m Ut[b][d][m] * (sum_n Wt[m][k][n] * Vt[b][d][n]) )
// grid 256 = (b, 64-d tile); 512 threads = 8 waves = 4 kt x 2 dh.
__global__ __launch_bounds__(512, 2) void layer_mfma(
    const unsigned short* __restrict__ Ut, const unsigned short* __restrict__ Vt,
    const unsigned short* __restrict__ Wt, unsigned short* __restrict__ Ot) {
  __shared__ uint4 wlds4[2][2048];  // 2 x 32KB: 4-m W chunks, double buffered

  const int t = threadIdx.x;
  const int l = t & 63, w = t >> 6;
  const int kt = w & 3, dh = w >> 2;
  const int b = blockIdx.x >> 3, d0 = (blockIdx.x & 7) << 6;
  const int l15 = l & 15, lg = l >> 4;

  // B fragments (v), resident all kernel: Bf[dt][h]
  bf16x8 Bf[2][2];
  const unsigned short* Vb = Vt + (b * 512 + d0 + dh * 32) * 64;
  #pragma unroll
  for (int dt = 0; dt < 2; ++dt)
    #pragma unroll
    for (int h = 0; h < 2; ++h)
      Bf[dt][h] = *(const bf16x8*)(Vb + (dt * 16 + l15) * 64 + h * 32 + lg * 8);

  // u values in registers: ureg[dt][mg] covers m = mg*8..+7 for this lane's d-col
  bf16x8 ureg[2][8];
  const unsigned short* Ub = Ut + (b * 512 + d0 + dh * 32) * 64;
  #pragma unroll
  for (int dt = 0; dt < 2; ++dt)
    #pragma unroll
    for (int mg = 0; mg < 8; ++mg)
      ureg[dt][mg] = *(const bf16x8*)(Ub + (dt * 16 + l15) * 64 + mg * 8);

  f32x4 acc0 = {0.f, 0.f, 0.f, 0.f}, acc1 = {0.f, 0.f, 0.f, 0.f};

  // stage chunk 0 (m = 0..3, 32KB)
  {
    uint4 st[4];
    #pragma unroll
    for (int j = 0; j < 4; ++j) st[j] = *(const uint4*)(Wt + j * 4096 + t * 8);
    #pragma unroll
    for (int j = 0; j < 4; ++j) wlds4[0][j * 512 + t] = st[j];
  }
  __syncthreads();

  // LDS A-frag offsets in 16B units: krow*8 + ((h*4+lg)^(krow&7))
  const int krow = kt * 16 + l15;
  const int kx = krow & 7;
  const int off0 = krow * 8 + ((0 + lg) ^ kx);
  const int off1 = krow * 8 + ((4 + lg) ^ kx);

  #pragma unroll
  for (int c = 0; c < 16; ++c) {
    const uint4* buf = wlds4[c & 1];
    uint4 nst[4];
    if (c < 15) {
      const unsigned short* Wn = Wt + (c + 1) * 16384;
      #pragma unroll
      for (int j = 0; j < 4; ++j) nst[j] = *(const uint4*)(Wn + j * 4096 + t * 8);
    }
    #pragma unroll
    for (int mm = 0; mm < 4; ++mm) {
      const int m = c * 4 + mm;
      bf16x8 a0 = *(const bf16x8*)&buf[mm * 512 + off0];
      bf16x8 a1 = *(const bf16x8*)&buf[mm * 512 + off1];
      f32x4 t0 = {0.f, 0.f, 0.f, 0.f}, t1 = {0.f, 0.f, 0.f, 0.f};
      t0 = __builtin_amdgcn_mfma_f32_16x16x32_bf16(a0, Bf[0][0], t0, 0, 0, 0);
      t0 = __builtin_amdgcn_mfma_f32_16x16x32_bf16(a1, Bf[0][1], t0, 0, 0, 0);
      t1 = __builtin_amdgcn_mfma_f32_16x16x32_bf16(a0, Bf[1][0], t1, 0, 0, 0);
      t1 = __builtin_amdgcn_mfma_f32_16x16x32_bf16(a1, Bf[1][1], t1, 0, 0, 0);
      const float u0 = bf2f((unsigned short)ureg[0][m >> 3][m & 7]);
      const float u1 = bf2f((unsigned short)ureg[1][m >> 3][m & 7]);
      #pragma unroll
      for (int r = 0; r < 4; ++r) {
        acc0[r] += u0 * t0[r];
        acc1[r] += u1 * t1[r];
      }
    }
    if (c < 15) {
      #pragma unroll
      for (int j = 0; j < 4; ++j) wlds4[(c + 1) & 1][j * 512 + t] = nst[j];
    }
    __syncthreads();
  }

  // epilogue: relu + bf16 + store to Ot[b][d][k] (4 contiguous k per lane per dt)
  #pragma unroll
  for (int dt = 0; dt < 2; ++dt) {
    const f32x4 a = dt ? acc1 : acc0;
    const int d = d0 + dh * 32 + dt * 16 + l15;
    unsigned short* op = Ot + (b * 512 + d) * 64 + kt * 16 + lg * 4;
    ushort4 o;
    o.x = f2bf(fmaxf(a[0], 0.f));
    o.y = f2bf(fmaxf(a[1], 0.f));
    o.z = f2bf(fmaxf(a[2], 0.f));
    o.w = f2bf(fmaxf(a[3], 0.f));
    *(ushort4*)op = o;
  }
}

// out[b,p,d] = LN_d( x[b,p,d] + pb[p] + sum_t pw[p][t]*X1t[b][d][t] + pw[p][64+t]*X2t[b][d][t] )
// grid 256 = (b, p-oct); 512 threads = d.
__global__ __launch_bounds__(512, 2) void proj_ln(
    const float* __restrict__ x, const unsigned short* __restrict__ X1t,
    const unsigned short* __restrict__ X2t, const float* __restrict__ pw,
    const float* __restrict__ pb, const float* __restrict__ gamma,
    const float* __restrict__ beta, float* __restrict__ out) {
  const int b = blockIdx.x >> 3, pg = blockIdx.x & 7;
  const int d = threadIdx.x;
  __shared__ float pws[8 * 128];
  __shared__ float pbs[8];
  __shared__ float red[8 * 16];  // [p][ {sum:0-7, sumsq:8-15} per wave ]

  for (int i = threadIdx.x; i < 1024; i += 512) pws[i] = pw[pg * 1024 + i];
  if (threadIdx.x < 8) pbs[threadIdx.x] = pb[pg * 8 + threadIdx.x];
  __syncthreads();

  // load + convert this d-column's 128 cin values
  float c1[64], c2[64];
  const unsigned short* r1 = X1t + (b * 512 + d) * 64;
  const unsigned short* r2 = X2t + (b * 512 + d) * 64;
  #pragma unroll
  for (int g = 0; g < 8; ++g) {
    bf16x8 v1 = *(const bf16x8*)(r1 + g * 8);
    bf16x8 v2 = *(const bf16x8*)(r2 + g * 8);
    #pragma unroll
    for (int jj = 0; jj < 8; ++jj) {
      c1[g * 8 + jj] = bf2f((unsigned short)v1[jj]);
      c2[g * 8 + jj] = bf2f((unsigned short)v2[jj]);
    }
  }
  const int wv = d >> 6, ln = d & 63;
  float yv[8];

  #pragma unroll
  for (int pi = 0; pi < 8; ++pi) {
    float s = 0.f;
    #pragma unroll
    for (int t4 = 0; t4 < 16; ++t4) {
      float4 w4 = *(const float4*)&pws[pi * 128 + t4 * 4];
      s += w4.x * c1[t4 * 4] + w4.y * c1[t4 * 4 + 1] + w4.z * c1[t4 * 4 + 2] + w4.w * c1[t4 * 4 + 3];
    }
    #pragma unroll
    for (int t4 = 0; t4 < 16; ++t4) {
      float4 w4 = *(const float4*)&pws[pi * 128 + 64 + t4 * 4];
      s += w4.x * c2[t4 * 4] + w4.y * c2[t4 * 4 + 1] + w4.z * c2[t4 * 4 + 2] + w4.w * c2[t4 * 4 + 3];
    }
    const int p = pg * 8 + pi;
    const float y = x[(b * 64 + p) * 512 + d] + pbs[pi] + s;
    yv[pi] = y;
    float sm = y, sq = y * y;
    #pragma unroll
    for (int off = 32; off > 0; off >>= 1) {
      sm += __shfl_xor(sm, off);
      sq += __shfl_xor(sq, off);
    }
    if (ln == 0) { red[pi * 16 + wv] = sm; red[pi * 16 + 8 + wv] = sq; }
  }
  __syncthreads();

  const float gam = gamma[d], bet = beta[d];
  #pragma unroll
  for (int pi = 0; pi < 8; ++pi) {
    float sum = 0.f, sumsq = 0.f;
    #pragma unroll
    for (int j = 0; j < 8; ++j) { sum += red[pi * 16 + j]; sumsq += red[pi * 16 + 8 + j]; }
    const float mu = sum * (1.f / 512.f);
    const float var = sumsq * (1.f / 512.f) - mu * mu;
    const float rs = rsqrtf(var + 1e-5f);
    const int p = pg * 8 + pi;
    out[(b * 64 + p) * 512 + d] = gam * (yv[pi] - mu) * rs + bet;
  }
}

extern "C" void kernel_launch(void* const* d_in, const int* in_sizes, int n_in,
                              void* d_out, int out_size, void* d_ws, size_t ws_size,
                              hipStream_t stream) {
  const float* x     = (const float*)d_in[0];
  const float* W1    = (const float*)d_in[1];
  const float* W2    = (const float*)d_in[2];
  const float* pw    = (const float*)d_in[3];
  const float* pb    = (const float*)d_in[4];
  const float* gamma = (const float*)d_in[5];
  const float* beta  = (const float*)d_in[6];
  float* out = (float*)d_out;

  char* ws = (char*)d_ws;
  unsigned short* xt  = (unsigned short*)(ws);                 // 2MB  [32][512][64]
  unsigned short* X1t = (unsigned short*)(ws + (2u << 20));    // 2MB
  unsigned short* X2t = (unsigned short*)(ws + (4u << 20));    // 2MB
  unsigned short* W1t = (unsigned short*)(ws + (6u << 20));    // 512KB [64][64][64] swz
  unsigned short* W2t = (unsigned short*)(ws + (6u << 20) + (512u << 10));

  transpose_x<<<dim3(256), dim3(256), 0, stream>>>(x, xt);
  transpose_w<<<dim3(128), dim3(256), 0, stream>>>(W1, W2, W1t, W2t);
  layer_mfma<<<dim3(256), dim3(512), 0, stream>>>(xt, xt, W1t, X1t);
  layer_mfma<<<dim3(256), dim3(512), 0, stream>>>(X1t, xt, W2t, X2t);
  proj_ln<<<dim3(256), dim3(512), 0, stream>>>(x, X1t, X2t, pw, pb, gamma, beta, out);
}

// Round 7
// 61.928 us; speedup vs baseline: 6.9296x; 3.0899x over previous
//
#include <hip/hip_runtime.h>

typedef __attribute__((ext_vector_type(8))) short bf16x8;
typedef __attribute__((ext_vector_type(4))) float f32x4;
typedef __attribute__((ext_vector_type(8))) unsigned short u16x8;

__device__ __forceinline__ unsigned short f2bf(float f) {
  union { float f; unsigned u; } v; v.f = f;
  unsigned r = v.u + 0x7FFF + ((v.u >> 16) & 1);
  return (unsigned short)(r >> 16);
}
__device__ __forceinline__ float bf2f(unsigned short s) {
  union { unsigned u; float f; } v; v.u = ((unsigned)s) << 16;
  return v.f;
}
__device__ __forceinline__ void gll16(const unsigned short* g, unsigned short* l) {
  __builtin_amdgcn_global_load_lds(
      (const __attribute__((address_space(1))) void*)g,
      (__attribute__((address_space(3))) void*)l, 16, 0, 0);
}
// Drain LDS-DMA before a buffer-handoff barrier. The compiler is NOT
// guaranteed to treat global_load_lds as barrier-relevant; without this an
// other-wave consumer can read a W chunk whose DMA hasn't landed (replay race).
__device__ __forceinline__ void dma_fence() {
  asm volatile("s_waitcnt vmcnt(0)" ::: "memory");
  __builtin_amdgcn_sched_barrier(0);
}

// x[32][64][512] f32 -> xt[32][512][64] bf16 (transpose m<->d per b)
__global__ __launch_bounds__(256) void transpose_x(const float* __restrict__ x,
                                                   unsigned short* __restrict__ xt) {
  __shared__ float xs[64 * 64];
  const int b = blockIdx.x >> 3, d0 = (blockIdx.x & 7) << 6;
  const int t = threadIdx.x;
  #pragma unroll
  for (int i = 0; i < 4; ++i) {
    const int idx = i * 256 + t;
    const int m = idx >> 4, c = idx & 15;
    float4 v = *(const float4*)&x[((b << 6) + m) * 512 + d0 + (c << 2)];
    *(float4*)&xs[(m << 6) + (c << 2)] = v;
  }
  __syncthreads();
  #pragma unroll
  for (int j = 0; j < 2; ++j) {
    const int idx = j * 256 + t;
    const int dl = idx >> 3, g = idx & 7;
    u16x8 o;
    #pragma unroll
    for (int jj = 0; jj < 8; ++jj) o[jj] = f2bf(xs[(((g << 3) + jj) << 6) + dl]);
    *(u16x8*)&xt[((b * 512) + d0 + dl) * 64 + (g << 3)] = o;
  }
}

// W[m][n][k] f32 -> Wt[m][k][n] bf16, 16B-chunk XOR swizzle: slot = g ^ (k&7)
__global__ __launch_bounds__(256) void transpose_w(const float* __restrict__ W1,
                                                   const float* __restrict__ W2,
                                                   unsigned short* __restrict__ W1t,
                                                   unsigned short* __restrict__ W2t) {
  __shared__ float ws_[64 * 64];
  const int m = blockIdx.x & 63, sel = blockIdx.x >> 6;
  const float* src = (sel ? W2 : W1) + m * 4096;
  unsigned short* dst = (sel ? W2t : W1t) + m * 4096;
  const int t = threadIdx.x;
  #pragma unroll
  for (int i = 0; i < 4; ++i) {
    const int idx = i * 256 + t;
    *(float4*)&ws_[idx << 2] = *(const float4*)&src[idx << 2];
  }
  __syncthreads();
  #pragma unroll
  for (int j = 0; j < 2; ++j) {
    const int idx = j * 256 + t;
    const int k = idx >> 3, g = idx & 7;
    u16x8 o;
    #pragma unroll
    for (int jj = 0; jj < 8; ++jj) o[jj] = f2bf(ws_[(((g << 3) + jj) << 6) + k]);
    const int slot = g ^ (k & 7);
    *(u16x8*)&dst[(k << 6) + (slot << 3)] = o;
  }
}

// Okd[b][k][d] = relu( sum_m U[b][m][d] * (sum_n Wt[m][k][n] * Vt[b][d][n]) )
// U is row-major [b][64][512]: f32 (UF32=1, layer1 reads x) or bf16 (layer2 reads X1kd).
// grid 256 = (b, 64-d tile); 512 threads = 8 waves = 4 kt x 2 dh.
// Dynamic LDS 72KB: wbuf0[32KB] | wbuf1[32KB] | u_lds[8KB]
template <int UF32>
__global__ __launch_bounds__(512) void layer_mfma(
    const void* __restrict__ Uraw, const unsigned short* __restrict__ Vt,
    const unsigned short* __restrict__ Wt, unsigned short* __restrict__ Okd) {
  extern __shared__ char smem[];
  unsigned short* wbuf0 = (unsigned short*)smem;
  unsigned short* wbuf1 = (unsigned short*)(smem + 32768);
  unsigned short* u_lds = (unsigned short*)(smem + 65536);

  const int t = threadIdx.x;
  const int l = t & 63, w = t >> 6;
  const int kt = w & 3, dh = w >> 2;
  const int b = blockIdx.x >> 3, d0 = (blockIdx.x & 7) << 6;
  const int l15 = l & 15, lg = l >> 4;

  // stage u: u_lds[m][d_local] bf16 (one u16x8 write per thread)
  {
    const int m = t >> 3, ch = t & 7;
    if (UF32) {
      const float* U = (const float*)Uraw;
      const float* src = U + ((b << 6) + m) * 512 + d0 + (ch << 3);
      float4 a = *(const float4*)src;
      float4 c = *(const float4*)(src + 4);
      u16x8 o;
      o[0] = f2bf(a.x); o[1] = f2bf(a.y); o[2] = f2bf(a.z); o[3] = f2bf(a.w);
      o[4] = f2bf(c.x); o[5] = f2bf(c.y); o[6] = f2bf(c.z); o[7] = f2bf(c.w);
      *(u16x8*)&u_lds[(m << 6) + (ch << 3)] = o;
    } else {
      const unsigned short* U = (const unsigned short*)Uraw;
      *(u16x8*)&u_lds[(m << 6) + (ch << 3)] =
          *(const u16x8*)(U + ((b << 6) + m) * 512 + d0 + (ch << 3));
    }
  }

  // B fragments (v), resident in regs: Bf[dt][h]
  bf16x8 Bf[2][2];
  const unsigned short* Vb = Vt + (b * 512 + d0 + dh * 32) * 64;
  #pragma unroll
  for (int dt = 0; dt < 2; ++dt)
    #pragma unroll
    for (int h = 0; h < 2; ++h)
      Bf[dt][h] = *(const bf16x8*)(Vb + (dt * 16 + l15) * 64 + h * 32 + lg * 8);

  // stage W chunk 0 (m=0..3, 32KB) directly to LDS
  #pragma unroll
  for (int j = 0; j < 4; ++j) gll16(Wt + j * 4096 + t * 8, wbuf0 + j * 4096 + t * 8);
  dma_fence();
  __syncthreads();

  // A-frag LDS offsets (shorts): krow*64 + (slot^kx)*8 within an m-slice of 4096
  const int krow = kt * 16 + l15;
  const int kx = krow & 7;
  const int aoff0 = krow * 64 + ((0 + lg) ^ kx) * 8;  // h=0
  const int aoff1 = krow * 64 + ((4 + lg) ^ kx) * 8;  // h=1

  f32x4 acc0 = {0.f, 0.f, 0.f, 0.f}, acc1 = {0.f, 0.f, 0.f, 0.f};

  for (int c = 0; c < 16; ++c) {
    unsigned short* cur = (c & 1) ? wbuf1 : wbuf0;
    unsigned short* nxt = (c & 1) ? wbuf0 : wbuf1;
    if (c < 15) {
      const unsigned short* wsrc = Wt + (c + 1) * 16384;
      #pragma unroll
      for (int j = 0; j < 4; ++j) gll16(wsrc + j * 4096 + t * 8, nxt + j * 4096 + t * 8);
    }
    #pragma unroll
    for (int mm = 0; mm < 4; ++mm) {
      const int m = (c << 2) + mm;
      bf16x8 a0 = *(const bf16x8*)(cur + mm * 4096 + aoff0);
      bf16x8 a1 = *(const bf16x8*)(cur + mm * 4096 + aoff1);
      f32x4 t0 = {0.f, 0.f, 0.f, 0.f}, t1 = {0.f, 0.f, 0.f, 0.f};
      t0 = __builtin_amdgcn_mfma_f32_16x16x32_bf16(a0, Bf[0][0], t0, 0, 0, 0);
      t0 = __builtin_amdgcn_mfma_f32_16x16x32_bf16(a1, Bf[0][1], t0, 0, 0, 0);
      t1 = __builtin_amdgcn_mfma_f32_16x16x32_bf16(a0, Bf[1][0], t1, 0, 0, 0);
      t1 = __builtin_amdgcn_mfma_f32_16x16x32_bf16(a1, Bf[1][1], t1, 0, 0, 0);
      const float u0 = bf2f(u_lds[m * 64 + dh * 32 + l15]);
      const float u1 = bf2f(u_lds[m * 64 + dh * 32 + 16 + l15]);
      #pragma unroll
      for (int r = 0; r < 4; ++r) {
        acc0[r] += u0 * t0[r];
        acc1[r] += u1 * t1[r];
      }
    }
    // The next iteration reads `nxt` (this iteration's DMA target) and
    // overwrites `cur`. Both require: DMA landed AND all waves past reads.
    dma_fence();
    __syncthreads();
  }

  // epilogue: relu + bf16, store Okd[b][k][d]
  #pragma unroll
  for (int dt = 0; dt < 2; ++dt) {
    const f32x4 a = dt ? acc1 : acc0;
    const int d = d0 + dh * 32 + dt * 16 + l15;
    #pragma unroll
    for (int r = 0; r < 4; ++r) {
      const int k = kt * 16 + lg * 4 + r;
      Okd[((b << 6) + k) * 512 + d] = f2bf(fmaxf(a[r], 0.f));
    }
  }
}

// out[b,p,d] = LN_d( x[b,p,d] + pb[p] + sum_t pw[p,t]*X1kd[b][t][d] + pw[p,64+t]*X2kd[b][t][d] )
// grid 256 = (b, 8-p group); 512 threads = d.
__global__ __launch_bounds__(512) void proj_ln(
    const float* __restrict__ x, const unsigned short* __restrict__ X1kd,
    const unsigned short* __restrict__ X2kd, const float* __restrict__ pw,
    const float* __restrict__ pb, const float* __restrict__ gamma,
    const float* __restrict__ beta, float* __restrict__ out) {
  const int b = blockIdx.x >> 3, pg = blockIdx.x & 7;
  const int d = threadIdx.x;
  __shared__ float red[8 * 16];

  float s[8] = {0.f, 0.f, 0.f, 0.f, 0.f, 0.f, 0.f, 0.f};
  const float* pwb = pw + pg * 8 * 128;  // block-uniform rows
  const unsigned short* r1 = X1kd + (b << 6) * 512 + d;
  const unsigned short* r2 = X2kd + (b << 6) * 512 + d;

  #pragma unroll 4
  for (int tt = 0; tt < 64; ++tt) {
    const float c = bf2f(r1[tt * 512]);
    #pragma unroll
    for (int pi = 0; pi < 8; ++pi) s[pi] += pwb[pi * 128 + tt] * c;
  }
  #pragma unroll 4
  for (int tt = 0; tt < 64; ++tt) {
    const float c = bf2f(r2[tt * 512]);
    #pragma unroll
    for (int pi = 0; pi < 8; ++pi) s[pi] += pwb[pi * 128 + 64 + tt] * c;
  }

  const int wv = d >> 6, ln = d & 63;
  float yv[8];
  #pragma unroll
  for (int pi = 0; pi < 8; ++pi) {
    const int p = pg * 8 + pi;
    const float y = x[((b << 6) + p) * 512 + d] + pb[p] + s[pi];
    yv[pi] = y;
    float sm = y, sq = y * y;
    #pragma unroll
    for (int off = 32; off > 0; off >>= 1) {
      sm += __shfl_xor(sm, off);
      sq += __shfl_xor(sq, off);
    }
    if (ln == 0) { red[pi * 16 + wv] = sm; red[pi * 16 + 8 + wv] = sq; }
  }
  __syncthreads();

  const float gam = gamma[d], bet = beta[d];
  #pragma unroll
  for (int pi = 0; pi < 8; ++pi) {
    float sum = 0.f, sumsq = 0.f;
    #pragma unroll
    for (int j = 0; j < 8; ++j) { sum += red[pi * 16 + j]; sumsq += red[pi * 16 + 8 + j]; }
    const float mu = sum * (1.f / 512.f);
    const float var = sumsq * (1.f / 512.f) - mu * mu;
    const float rs = rsqrtf(var + 1e-5f);
    const int p = pg * 8 + pi;
    out[((b << 6) + p) * 512 + d] = gam * (yv[pi] - mu) * rs + bet;
  }
}

extern "C" void kernel_launch(void* const* d_in, const int* in_sizes, int n_in,
                              void* d_out, int out_size, void* d_ws, size_t ws_size,
                              hipStream_t stream) {
  const float* x     = (const float*)d_in[0];
  const float* W1    = (const float*)d_in[1];
  const float* W2    = (const float*)d_in[2];
  const float* pw    = (const float*)d_in[3];
  const float* pb    = (const float*)d_in[4];
  const float* gamma = (const float*)d_in[5];
  const float* beta  = (const float*)d_in[6];
  float* out = (float*)d_out;

  char* ws = (char*)d_ws;
  unsigned short* xt   = (unsigned short*)(ws);                          // 2MB [32][512][64]
  unsigned short* X1kd = (unsigned short*)(ws + (2u << 20));             // 2MB [32][64][512]
  unsigned short* X2kd = (unsigned short*)(ws + (4u << 20));             // 2MB [32][64][512]
  unsigned short* W1t  = (unsigned short*)(ws + (6u << 20));             // 512KB
  unsigned short* W2t  = (unsigned short*)(ws + (6u << 20) + (512u << 10));

  transpose_x<<<dim3(256), dim3(256), 0, stream>>>(x, xt);
  transpose_w<<<dim3(128), dim3(256), 0, stream>>>(W1, W2, W1t, W2t);
  layer_mfma<1><<<dim3(256), dim3(512), 73728, stream>>>((const void*)x, xt, W1t, X1kd);
  layer_mfma<0><<<dim3(256), dim3(512), 73728, stream>>>((const void*)X1kd, xt, W2t, X2kd);
  proj_ln<<<dim3(256), dim3(512), 0, stream>>>(x, X1kd, X2kd, pw, pb, gamma, beta, out);
}

// Round 8
// 50.814 us; speedup vs baseline: 8.4452x; 1.2187x over previous
//
#include <hip/hip_runtime.h>

typedef __attribute__((ext_vector_type(8))) short bf16x8;
typedef __attribute__((ext_vector_type(4))) float f32x4;
typedef __attribute__((ext_vector_type(8))) unsigned short u16x8;

__device__ __forceinline__ unsigned short f2bf(float f) {
  union { float f; unsigned u; } v; v.f = f;
  unsigned r = v.u + 0x7FFF + ((v.u >> 16) & 1);
  return (unsigned short)(r >> 16);
}
__device__ __forceinline__ float bf2f(unsigned short s) {
  union { unsigned u; float f; } v; v.u = ((unsigned)s) << 16;
  return v.f;
}
__device__ __forceinline__ void gll16(const unsigned short* g, unsigned short* l) {
  __builtin_amdgcn_global_load_lds(
      (const __attribute__((address_space(1))) void*)g,
      (__attribute__((address_space(3))) void*)l, 16, 0, 0);
}

// W[m][n][k] f32 -> Wt[m][k][n] bf16, 16B-chunk XOR swizzle: slot = g ^ (k&7)
__global__ __launch_bounds__(256) void transpose_w(const float* __restrict__ W1,
                                                   const float* __restrict__ W2,
                                                   unsigned short* __restrict__ W1t,
                                                   unsigned short* __restrict__ W2t) {
  __shared__ float ws_[64 * 64];
  const int m = blockIdx.x & 63, sel = blockIdx.x >> 6;
  const float* src = (sel ? W2 : W1) + m * 4096;
  unsigned short* dst = (sel ? W2t : W1t) + m * 4096;
  const int t = threadIdx.x;
  #pragma unroll
  for (int i = 0; i < 4; ++i) {
    const int idx = i * 256 + t;
    *(float4*)&ws_[idx << 2] = *(const float4*)&src[idx << 2];
  }
  __syncthreads();
  #pragma unroll
  for (int j = 0; j < 2; ++j) {
    const int idx = j * 256 + t;
    const int k = idx >> 3, g = idx & 7;
    u16x8 o;
    #pragma unroll
    for (int jj = 0; jj < 8; ++jj) o[jj] = f2bf(ws_[(((g << 3) + jj) << 6) + k]);
    const int slot = g ^ (k & 7);
    *(u16x8*)&dst[(k << 6) + (slot << 3)] = o;
  }
}

// One layer pass: stream 16 W-chunks (4 m-slices each) through a 3-buffer
// counted-vmcnt pipeline; accumulate acc = sum_m u[m]*(W[m] row x v).
// Pipeline invariants (per wave; vmcnt retires in issue order):
//  - prologue: issue c0,c1; wait vmcnt(4) -> c0 landed (+ any older stores drained).
//  - iter c: issue c+2; compute from buf[c%3]; wait vmcnt(4) -> c+1 landed
//    (outstanding = {c+1:4, c+2:4}); s_barrier.
//  - buf[(c+2)%3] overwrite is safe: its readers (iter c-1) passed the barrier
//    at end of iter c-1, which precedes this issue.
__device__ __forceinline__ void layer_pass(
    const unsigned short* __restrict__ Wt, unsigned short* wbuf,
    const unsigned short* u_lds, const bf16x8 (&Bf)[2][2],
    f32x4& acc0, f32x4& acc1,
    int aoff0, int aoff1, int uoff0, int uoff1, int t) {
  // issue chunk0 -> buf0, chunk1 -> buf1
  #pragma unroll
  for (int j = 0; j < 4; ++j) gll16(Wt + j * 4096 + t * 8, wbuf + j * 4096 + t * 8);
  #pragma unroll
  for (int j = 0; j < 4; ++j)
    gll16(Wt + 16384 + j * 4096 + t * 8, wbuf + 16384 + j * 4096 + t * 8);
  __builtin_amdgcn_sched_barrier(0);
  asm volatile("s_waitcnt vmcnt(4) lgkmcnt(0)" ::: "memory");
  __builtin_amdgcn_sched_barrier(0);
  __builtin_amdgcn_s_barrier();
  __builtin_amdgcn_sched_barrier(0);

  acc0 = (f32x4){0.f, 0.f, 0.f, 0.f};
  acc1 = (f32x4){0.f, 0.f, 0.f, 0.f};

  #pragma unroll
  for (int c = 0; c < 16; ++c) {
    if (c + 2 < 16) {
      const unsigned short* wsrc = Wt + (c + 2) * 16384;
      unsigned short* dst = wbuf + ((c + 2) % 3) * 16384;
      #pragma unroll
      for (int j = 0; j < 4; ++j) gll16(wsrc + j * 4096 + t * 8, dst + j * 4096 + t * 8);
    }
    const unsigned short* bufc = wbuf + (c % 3) * 16384;
    #pragma unroll
    for (int mm = 0; mm < 4; ++mm) {
      const int m = (c << 2) + mm;
      bf16x8 a0 = *(const bf16x8*)(bufc + mm * 4096 + aoff0);
      bf16x8 a1 = *(const bf16x8*)(bufc + mm * 4096 + aoff1);
      f32x4 t0 = {0.f, 0.f, 0.f, 0.f}, t1 = {0.f, 0.f, 0.f, 0.f};
      t0 = __builtin_amdgcn_mfma_f32_16x16x32_bf16(a0, Bf[0][0], t0, 0, 0, 0);
      t0 = __builtin_amdgcn_mfma_f32_16x16x32_bf16(a1, Bf[0][1], t0, 0, 0, 0);
      t1 = __builtin_amdgcn_mfma_f32_16x16x32_bf16(a0, Bf[1][0], t1, 0, 0, 0);
      t1 = __builtin_amdgcn_mfma_f32_16x16x32_bf16(a1, Bf[1][1], t1, 0, 0, 0);
      const float u0 = bf2f(u_lds[m * 64 + uoff0]);
      const float u1 = bf2f(u_lds[m * 64 + uoff1]);
      #pragma unroll
      for (int r = 0; r < 4; ++r) {
        acc0[r] += u0 * t0[r];
        acc1[r] += u1 * t1[r];
      }
    }
    __builtin_amdgcn_sched_barrier(0);
    if (c < 14) {
      asm volatile("s_waitcnt vmcnt(4)" ::: "memory");
    } else if (c == 14) {
      asm volatile("s_waitcnt vmcnt(0)" ::: "memory");
    }
    __builtin_amdgcn_sched_barrier(0);
    if (c < 15) {
      __builtin_amdgcn_s_barrier();
      __builtin_amdgcn_sched_barrier(0);
    }
  }
  __syncthreads();  // all waves done with last buffer + u_lds reads
}

// Fused both cross layers. Block = (b, 64-d tile); 512 threads = 8 waves
// = 4 kt x 2 dh. Per-column independence: layer2's u = relu(X1) columns,
// produced in-block and passed via u_lds transpose.
// Dynamic LDS 104KB: wbuf[3][32KB] | u_lds[8KB]
__global__ __launch_bounds__(512) void fused_layers(
    const float* __restrict__ x,
    const unsigned short* __restrict__ W1t, const unsigned short* __restrict__ W2t,
    unsigned short* __restrict__ X1kd, unsigned short* __restrict__ X2kd) {
  extern __shared__ char smem[];
  unsigned short* wbuf = (unsigned short*)smem;              // 3 * 16384 shorts
  unsigned short* u_lds = (unsigned short*)(smem + 98304);   // 4096 shorts

  const int t = threadIdx.x;
  const int l = t & 63, w = t >> 6;
  const int kt = w & 3, dh = w >> 2;
  const int b = blockIdx.x >> 3, d0 = (blockIdx.x & 7) << 6;
  const int l15 = l & 15, lg = l >> 4;

  // stage u1 = x[b, m, d-tile] -> u_lds[m][d_local] bf16
  {
    const int m = t >> 3, ch = t & 7;
    const float* src = x + ((b << 6) + m) * 512 + d0 + (ch << 3);
    float4 a = *(const float4*)src;
    float4 c4 = *(const float4*)(src + 4);
    u16x8 o;
    o[0] = f2bf(a.x); o[1] = f2bf(a.y); o[2] = f2bf(a.z); o[3] = f2bf(a.w);
    o[4] = f2bf(c4.x); o[5] = f2bf(c4.y); o[6] = f2bf(c4.z); o[7] = f2bf(c4.w);
    *(u16x8*)&u_lds[(m << 6) + (ch << 3)] = o;
  }

  // B fragments straight from x (V = X0 for BOTH layers):
  // Bf[dt][h][jj] = bf16(x[b, h*32+lg*8+jj, d0+dh*32+dt*16+l15])
  bf16x8 Bf[2][2];
  {
    const float* xb = x + (b << 6) * 512 + d0 + dh * 32 + l15;
    #pragma unroll
    for (int dt = 0; dt < 2; ++dt)
      #pragma unroll
      for (int h = 0; h < 2; ++h) {
        bf16x8 o;
        #pragma unroll
        for (int jj = 0; jj < 8; ++jj)
          o[jj] = (short)f2bf(xb[(h * 32 + lg * 8 + jj) * 512 + dt * 16]);
        Bf[dt][h] = o;
      }
  }

  const int krow = kt * 16 + l15;
  const int kx = krow & 7;
  const int aoff0 = krow * 64 + ((0 + lg) ^ kx) * 8;
  const int aoff1 = krow * 64 + ((4 + lg) ^ kx) * 8;
  const int uoff0 = dh * 32 + l15, uoff1 = dh * 32 + 16 + l15;

  f32x4 acc0, acc1;

  // ---- layer 1 ----
  layer_pass(W1t, wbuf, u_lds, Bf, acc0, acc1, aoff0, aoff1, uoff0, uoff1, t);

  // epilogue 1: relu -> global X1kd AND u_lds (u for layer 2).
  // Safe: layer_pass ended with __syncthreads(); each lane writes disjoint slots.
  #pragma unroll
  for (int dt = 0; dt < 2; ++dt) {
    const f32x4 a = dt ? acc1 : acc0;
    #pragma unroll
    for (int r = 0; r < 4; ++r) {
      const int k = kt * 16 + lg * 4 + r;
      const int dl = dh * 32 + dt * 16 + l15;
      const unsigned short hv = f2bf(fmaxf(a[r], 0.f));
      X1kd[((b << 6) + k) * 512 + d0 + dl] = hv;
      u_lds[k * 64 + dl] = hv;
    }
  }
  // layer_pass prologue does lgkmcnt(0) + s_barrier (u2 visibility) and its
  // vmcnt(4) also retires the 16 X1 stores (older in queue than chunk1).

  // ---- layer 2 ----
  layer_pass(W2t, wbuf, u_lds, Bf, acc0, acc1, aoff0, aoff1, uoff0, uoff1, t);

  // epilogue 2
  #pragma unroll
  for (int dt = 0; dt < 2; ++dt) {
    const f32x4 a = dt ? acc1 : acc0;
    #pragma unroll
    for (int r = 0; r < 4; ++r) {
      const int k = kt * 16 + lg * 4 + r;
      const int dl = dh * 32 + dt * 16 + l15;
      X2kd[((b << 6) + k) * 512 + d0 + dl] = f2bf(fmaxf(a[r], 0.f));
    }
  }
}

// out[b,p,d] = LN_d( x[b,p,d] + pb[p] + sum_t pw[p,t]*X1kd[b][t][d] + pw[p,64+t]*X2kd[b][t][d] )
// grid 256 = (b, 8-p group); 512 threads = d.
__global__ __launch_bounds__(512) void proj_ln(
    const float* __restrict__ x, const unsigned short* __restrict__ X1kd,
    const unsigned short* __restrict__ X2kd, const float* __restrict__ pw,
    const float* __restrict__ pb, const float* __restrict__ gamma,
    const float* __restrict__ beta, float* __restrict__ out) {
  const int b = blockIdx.x >> 3, pg = blockIdx.x & 7;
  const int d = threadIdx.x;
  __shared__ float red[8 * 16];

  float s[8] = {0.f, 0.f, 0.f, 0.f, 0.f, 0.f, 0.f, 0.f};
  const float* pwb = pw + pg * 8 * 128;  // block-uniform rows
  const unsigned short* r1 = X1kd + (b << 6) * 512 + d;
  const unsigned short* r2 = X2kd + (b << 6) * 512 + d;

  #pragma unroll 4
  for (int tt = 0; tt < 64; ++tt) {
    const float c = bf2f(r1[tt * 512]);
    #pragma unroll
    for (int pi = 0; pi < 8; ++pi) s[pi] += pwb[pi * 128 + tt] * c;
  }
  #pragma unroll 4
  for (int tt = 0; tt < 64; ++tt) {
    const float c = bf2f(r2[tt * 512]);
    #pragma unroll
    for (int pi = 0; pi < 8; ++pi) s[pi] += pwb[pi * 128 + 64 + tt] * c;
  }

  const int wv = d >> 6, ln = d & 63;
  float yv[8];
  #pragma unroll
  for (int pi = 0; pi < 8; ++pi) {
    const int p = pg * 8 + pi;
    const float y = x[((b << 6) + p) * 512 + d] + pb[p] + s[pi];
    yv[pi] = y;
    float sm = y, sq = y * y;
    #pragma unroll
    for (int off = 32; off > 0; off >>= 1) {
      sm += __shfl_xor(sm, off);
      sq += __shfl_xor(sq, off);
    }
    if (ln == 0) { red[pi * 16 + wv] = sm; red[pi * 16 + 8 + wv] = sq; }
  }
  __syncthreads();

  const float gam = gamma[d], bet = beta[d];
  #pragma unroll
  for (int pi = 0; pi < 8; ++pi) {
    float sum = 0.f, sumsq = 0.f;
    #pragma unroll
    for (int j = 0; j < 8; ++j) { sum += red[pi * 16 + j]; sumsq += red[pi * 16 + 8 + j]; }
    const float mu = sum * (1.f / 512.f);
    const float var = sumsq * (1.f / 512.f) - mu * mu;
    const float rs = rsqrtf(var + 1e-5f);
    const int p = pg * 8 + pi;
    out[((b << 6) + p) * 512 + d] = gam * (yv[pi] - mu) * rs + bet;
  }
}

extern "C" void kernel_launch(void* const* d_in, const int* in_sizes, int n_in,
                              void* d_out, int out_size, void* d_ws, size_t ws_size,
                              hipStream_t stream) {
  const float* x     = (const float*)d_in[0];
  const float* W1    = (const float*)d_in[1];
  const float* W2    = (const float*)d_in[2];
  const float* pw    = (const float*)d_in[3];
  const float* pb    = (const float*)d_in[4];
  const float* gamma = (const float*)d_in[5];
  const float* beta  = (const float*)d_in[6];
  float* out = (float*)d_out;

  char* ws = (char*)d_ws;
  unsigned short* X1kd = (unsigned short*)(ws);                          // 2MB [32][64][512]
  unsigned short* X2kd = (unsigned short*)(ws + (2u << 20));             // 2MB [32][64][512]
  unsigned short* W1t  = (unsigned short*)(ws + (4u << 20));             // 512KB swz
  unsigned short* W2t  = (unsigned short*)(ws + (4u << 20) + (512u << 10));

  transpose_w<<<dim3(128), dim3(256), 0, stream>>>(W1, W2, W1t, W2t);
  fused_layers<<<dim3(256), dim3(512), 106496, stream>>>(x, W1t, W2t, X1kd, X2kd);
  proj_ln<<<dim3(256), dim3(512), 0, stream>>>(x, X1kd, X2kd, pw, pb, gamma, beta, out);
}